// Round 4
// baseline (664.813 us; speedup 1.0000x reference)
//
#include <hip/hip_runtime.h>
#include <cstdint>
#include <cstddef>

// Problem constants (fixed by the reference)
#define S_TOK   8192
#define DMODEL  2048
#define NEXP    64
#define CAP     128
#define COMBINE_ELEMS 67108864ULL            // 8192*64*128
#define OUT_ELEMS     134217793ULL           // 1 + 2*COMBINE + 64
#define OUT_F4        33554448ULL            // floor(OUT_ELEMS/4); tail elem 134217792

typedef float floatx4 __attribute__((ext_vector_type(4)));  // nontemporal-compatible

// jax.random.uniform(key(42)): JAX >= 0.5 threefry_partitionable path:
// bits[idx] = o0 ^ o1 of threefry2x32((0,42), (0, idx))
__device__ __forceinline__ unsigned rotl32(unsigned x, unsigned r) {
    return (x << r) | (x >> (32u - r));
}

__device__ __forceinline__ void threefry2x32(unsigned k0, unsigned k1,
                                             unsigned c0, unsigned c1,
                                             unsigned& o0, unsigned& o1) {
    unsigned ks[3] = {k0, k1, k0 ^ k1 ^ 0x1BD11BDAu};
    unsigned x0 = c0 + ks[0];
    unsigned x1 = c1 + ks[1];
    const unsigned rotA[4] = {13u, 15u, 26u, 6u};
    const unsigned rotB[4] = {17u, 29u, 16u, 24u};
#pragma unroll
    for (int i = 0; i < 5; ++i) {
        const unsigned* rr = (i & 1) ? rotB : rotA;
#pragma unroll
        for (int j = 0; j < 4; ++j) {
            x0 += x1;
            x1 = rotl32(x1, rr[j]);
            x1 ^= x0;
        }
        x0 += ks[(i + 1) % 3];
        x1 += ks[(i + 2) % 3] + (unsigned)(i + 1);
    }
    o0 = x0; o1 = x1;
}

__device__ __forceinline__ float jax_uniform_noise(unsigned idx) {
    unsigned o0, o1;
    threefry2x32(0u, 42u, 0u, idx, o0, o1);
    unsigned bits = o0 ^ o1;
    unsigned fb = (bits >> 9) | 0x3f800000u;
    float f;
    __builtin_memcpy(&f, &fb, 4);
    return f - 1.0f;
}

// ------ Kernel 1: fused d_out zero-fill + logits GEMM + softmax/argmax/stats ------
// blockIdx < 256  : GEMM block (128 thr): tile 32 tokens x 64 experts, BK=64,
//                   thread = 4 tok x 4 exp; then in-block softmax via LDS transpose,
//                   emits tok_expert/tok_gate/tok_noise + cnt/me_sum atomics.
//                   No logits round-trip to HBM.
// blockIdx >= 256 : zero-fill blocks: grid-stride nontemporal float4 stores over
//                   d_out (537 MB). GEMM+softmax overlaps under the write-BW floor.
#define GEMM_BLOCKS 256
#define ZERO_BLOCKS 4096
__global__ __launch_bounds__(128) void gemm_softmax_zero(const float* __restrict__ x,
                                                         const float* __restrict__ wg,
                                                         int* __restrict__ tok_expert,
                                                         float* __restrict__ tok_gate,
                                                         float* __restrict__ tok_noise,
                                                         int* __restrict__ cnt,
                                                         float* __restrict__ me_sum,
                                                         float* __restrict__ d_out) {
    if (blockIdx.x >= GEMM_BLOCKS) {
        const size_t zb = blockIdx.x - GEMM_BLOCKS;
        floatx4* o4 = (floatx4*)d_out;
        const floatx4 z = {0.f, 0.f, 0.f, 0.f};
        const size_t stride = (size_t)ZERO_BLOCKS * 128;
        for (size_t i = zb * 128 + threadIdx.x; i < OUT_F4; i += stride)
            __builtin_nontemporal_store(z, &o4[i]);
        if (zb == 0 && threadIdx.x == 0) d_out[OUT_ELEMS - 1] = 0.f;
        return;
    }

    __shared__ __align__(16) float xs[32][68];   // doubles as logits tile post-GEMM
    __shared__ __align__(16) float wsh[64][68];
    __shared__ float mep[2][64];
    const int tid = threadIdx.x;
    const int s0 = blockIdx.x * 32;
    const int g  = tid & 15;          // experts g, g+16, g+32, g+48
    const int ty = tid >> 4;          // tokens ty*4 .. ty*4+3
    float acc[4][4];
#pragma unroll
    for (int i = 0; i < 4; ++i)
#pragma unroll
        for (int j = 0; j < 4; ++j) acc[i][j] = 0.f;

    for (int k0 = 0; k0 < DMODEL; k0 += 64) {
#pragma unroll
        for (int i = 0; i < 4; ++i) {  // x chunk: 32x64 = 512 float4, 128 thr
            int slot = tid + i * 128;
            int r = slot >> 4, c4 = (slot & 15) * 4;
            float4 v = *(const float4*)&x[(size_t)(s0 + r) * DMODEL + k0 + c4];
            *(float4*)&xs[r][c4] = v;
        }
#pragma unroll
        for (int i = 0; i < 8; ++i) {  // wg chunk: 64x64 = 1024 float4
            int slot = tid + i * 128;
            int r = slot >> 4, c4 = (slot & 15) * 4;
            float4 v = *(const float4*)&wg[(size_t)r * DMODEL + k0 + c4];
            *(float4*)&wsh[r][c4] = v;
        }
        __syncthreads();
#pragma unroll
        for (int k4 = 0; k4 < 64; k4 += 4) {
            float4 xv[4], wv[4];
#pragma unroll
            for (int t = 0; t < 4; ++t) xv[t] = *(float4*)&xs[ty * 4 + t][k4];
#pragma unroll
            for (int j = 0; j < 4; ++j) wv[j] = *(float4*)&wsh[g + 16 * j][k4];
#pragma unroll
            for (int t = 0; t < 4; ++t)
#pragma unroll
                for (int j = 0; j < 4; ++j) {
                    acc[t][j] += xv[t].x * wv[j].x; acc[t][j] += xv[t].y * wv[j].y;
                    acc[t][j] += xv[t].z * wv[j].z; acc[t][j] += xv[t].w * wv[j].w;
                }
        }
        __syncthreads();
    }

    // ---- in-block softmax: park logits tile in xs (all xs reads are done) ----
#pragma unroll
    for (int t = 0; t < 4; ++t)
#pragma unroll
        for (int j = 0; j < 4; ++j)
            xs[ty * 4 + t][g + 16 * j] = acc[t][j];
    __syncthreads();

    const int lane = tid & 63;        // lane == expert
    const int w = tid >> 6;           // wave handles tokens w*16 .. w*16+15
    float me_acc = 0.f;
#pragma unroll
    for (int it = 0; it < 16; ++it) {
        const int trow = w * 16 + it;
        float v = xs[trow][lane];
        float m = v;
#pragma unroll
        for (int off = 32; off; off >>= 1) m = fmaxf(m, __shfl_xor(m, off));
        float ev = expf(v - m);
        float sum = ev;
#pragma unroll
        for (int off = 32; off; off >>= 1) sum += __shfl_xor(sum, off);
        float gate = ev / sum;
        me_acc += gate;

        float bv = gate; int bi = lane;
#pragma unroll
        for (int off = 32; off; off >>= 1) {
            float ov = __shfl_xor(bv, off);
            int   oi = __shfl_xor(bi, off);
            if (ov > bv || (ov == bv && oi < bi)) { bv = ov; bi = oi; }
        }
        if (lane == 0) {
            const int s = s0 + trow;
            tok_expert[s] = bi;
            tok_gate[s]   = bv;
            tok_noise[s]  = jax_uniform_noise((unsigned)(s * NEXP + bi));
            atomicAdd(&cnt[bi], 1);
        }
    }
    mep[w][lane] = me_acc;
    __syncthreads();
    if (tid < 64) atomicAdd(&me_sum[tid], mep[0][tid] + mep[1][tid]);
}

// ---- Kernel 2: per-expert top-capacity select + scatter; block 64 = l_aux/counts ----
#define MAXN 2048
__global__ __launch_bounds__(256) void select_finalize(const int* __restrict__ tok_expert,
                                                       const float* __restrict__ tok_gate,
                                                       const float* __restrict__ tok_noise,
                                                       const int* __restrict__ cnt,
                                                       const float* __restrict__ me_sum,
                                                       float* __restrict__ d_out) {
    if (blockIdx.x == NEXP) {
        if (threadIdx.x < 64) {
            const int e = threadIdx.x;
            float me = me_sum[e] / (float)S_TOK;
            int c = cnt[e];
            float ce = (float)c / (float)S_TOK;
            float p = me * ce;
#pragma unroll
            for (int off = 32; off; off >>= 1) p += __shfl_xor(p, off);
            if (e == 0) d_out[0] = p * (float)NEXP;
            d_out[1 + 2 * COMBINE_ELEMS + e] = (float)c;
        }
        return;
    }

    const int e = blockIdx.x;
    __shared__ int   toks[MAXN];
    __shared__ float noi[MAXN];
    __shared__ int   rnk[MAXN];
    __shared__ int   n_sh;
    if (threadIdx.x == 0) n_sh = 0;
    __syncthreads();

    for (int s = threadIdx.x; s < S_TOK; s += 256) {
        if (tok_expert[s] == e) {
            int i = atomicAdd(&n_sh, 1);
            if (i < MAXN) { toks[i] = s; noi[i] = tok_noise[s]; }
        }
    }
    __syncthreads();
    int n = n_sh; if (n > MAXN) n = MAXN;

    // rank by noise desc, ties -> lower token index (lax.top_k stability)
    for (int i = threadIdx.x; i < n; i += 256) {
        float vi = noi[i]; int si = toks[i];
        int r = 0;
        for (int j = 0; j < n; ++j) {
            float vj = noi[j];
            r += (vj > vi) || (vj == vi && toks[j] < si);
        }
        rnk[i] = r;
    }
    __syncthreads();

    for (int i = threadIdx.x; i < n; i += 256) {
        if (rnk[i] < CAP) {
            int si = toks[i];
            int loc = 0;  // cumsum slot among kept tokens, by token index
            for (int j = 0; j < n; ++j)
                loc += (rnk[j] < CAP) && (toks[j] < si);
            size_t base = 1ULL + (((size_t)si * NEXP + e) * CAP + (size_t)loc);
            d_out[base] = tok_gate[si];              // combine_weights
            d_out[base + COMBINE_ELEMS] = 1.0f;      // dispatch_mask
        }
    }
}

extern "C" void kernel_launch(void* const* d_in, const int* in_sizes, int n_in,
                              void* d_out, int out_size, void* d_ws, size_t ws_size,
                              hipStream_t stream) {
    const float* x  = (const float*)d_in[0];
    const float* wg = (const float*)d_in[1];
    float* out = (float*)d_out;
    float* ws  = (float*)d_ws;

    // ws layout (float offsets)
    int*   tok_expert = (int*)ws;           // 8192
    float* tok_gate   = ws + 8192;          // 8192
    float* tok_noise  = ws + 16384;         // 8192
    int*   cnt        = (int*)(ws + 24576); // 64
    float* me_sum     = ws + 24640;         // 64

    hipMemsetAsync(cnt, 0, 128 * sizeof(float), stream);  // cnt + me_sum
    gemm_softmax_zero<<<GEMM_BLOCKS + ZERO_BLOCKS, 128, 0, stream>>>(
        x, wg, tok_expert, tok_gate, tok_noise, cnt, me_sum, out);
    select_finalize<<<NEXP + 1, 256, 0, stream>>>(tok_expert, tok_gate, tok_noise,
                                                  cnt, me_sum, out);
}

// Round 5
// 650.062 us; speedup vs baseline: 1.0227x; 1.0227x over previous
//
#include <hip/hip_runtime.h>
#include <cstdint>
#include <cstddef>

// Problem constants (fixed by the reference)
#define S_TOK   8192
#define DMODEL  2048
#define NEXP    64
#define CAP     128
#define COMBINE_ELEMS 67108864ULL            // 8192*64*128
#define OUT_ELEMS     134217793ULL           // 1 + 2*COMBINE + 64
#define OUT_F4        33554448ULL            // floor(OUT_ELEMS/4); tail elem 134217792

typedef float floatx4 __attribute__((ext_vector_type(4)));  // nontemporal-compatible

// jax.random.uniform(key(42)): JAX >= 0.5 threefry_partitionable path:
// bits[idx] = o0 ^ o1 of threefry2x32((0,42), (0, idx))
__device__ __forceinline__ unsigned rotl32(unsigned x, unsigned r) {
    return (x << r) | (x >> (32u - r));
}

__device__ __forceinline__ void threefry2x32(unsigned k0, unsigned k1,
                                             unsigned c0, unsigned c1,
                                             unsigned& o0, unsigned& o1) {
    unsigned ks[3] = {k0, k1, k0 ^ k1 ^ 0x1BD11BDAu};
    unsigned x0 = c0 + ks[0];
    unsigned x1 = c1 + ks[1];
    const unsigned rotA[4] = {13u, 15u, 26u, 6u};
    const unsigned rotB[4] = {17u, 29u, 16u, 24u};
#pragma unroll
    for (int i = 0; i < 5; ++i) {
        const unsigned* rr = (i & 1) ? rotB : rotA;
#pragma unroll
        for (int j = 0; j < 4; ++j) {
            x0 += x1;
            x1 = rotl32(x1, rr[j]);
            x1 ^= x0;
        }
        x0 += ks[(i + 1) % 3];
        x1 += ks[(i + 2) % 3] + (unsigned)(i + 1);
    }
    o0 = x0; o1 = x1;
}

__device__ __forceinline__ float jax_uniform_noise(unsigned idx) {
    unsigned o0, o1;
    threefry2x32(0u, 42u, 0u, idx, o0, o1);
    unsigned bits = o0 ^ o1;
    unsigned fb = (bits >> 9) | 0x3f800000u;
    float f;
    __builtin_memcpy(&f, &fb, 4);
    return f - 1.0f;
}

// ------ Kernel 1: fused d_out zero-fill + logits GEMM + softmax/argmax ------
// blockIdx < 256  : GEMM block (128 thr): tile 32 tokens x 64 experts, BK=64,
//                   thread = 4 tok x 4 exp; then in-block softmax via LDS reuse,
//                   emits tok_expert/tok_gate/tok_noise + me_part[block][e].
//                   NO global atomics (R4's cnt/me_sum hot-line atomics were the
//                   regression: ~24K device atomics on ~4 L2 lines).
// blockIdx >= 256 : zero-fill blocks: grid-stride nontemporal float4 stores over
//                   d_out (537 MB). GEMM+softmax hides under the write-BW floor.
#define GEMM_BLOCKS 256
#define ZERO_BLOCKS 4096
__global__ __launch_bounds__(128) void gemm_softmax_zero(const float* __restrict__ x,
                                                         const float* __restrict__ wg,
                                                         int* __restrict__ tok_expert,
                                                         float* __restrict__ tok_gate,
                                                         float* __restrict__ tok_noise,
                                                         float* __restrict__ me_part,
                                                         float* __restrict__ d_out) {
    if (blockIdx.x >= GEMM_BLOCKS) {
        const size_t zb = blockIdx.x - GEMM_BLOCKS;
        floatx4* o4 = (floatx4*)d_out;
        const floatx4 z = {0.f, 0.f, 0.f, 0.f};
        const size_t stride = (size_t)ZERO_BLOCKS * 128;
        for (size_t i = zb * 128 + threadIdx.x; i < OUT_F4; i += stride)
            __builtin_nontemporal_store(z, &o4[i]);
        if (zb == 0 && threadIdx.x == 0) d_out[OUT_ELEMS - 1] = 0.f;
        return;
    }

    __shared__ __align__(16) float xs[32][68];   // doubles as logits tile post-GEMM
    __shared__ __align__(16) float wsh[64][68];
    __shared__ float mep[2][64];
    const int tid = threadIdx.x;
    const int s0 = blockIdx.x * 32;
    const int g  = tid & 15;          // experts g, g+16, g+32, g+48
    const int ty = tid >> 4;          // tokens ty*4 .. ty*4+3
    float acc[4][4];
#pragma unroll
    for (int i = 0; i < 4; ++i)
#pragma unroll
        for (int j = 0; j < 4; ++j) acc[i][j] = 0.f;

    for (int k0 = 0; k0 < DMODEL; k0 += 64) {
#pragma unroll
        for (int i = 0; i < 4; ++i) {  // x chunk: 32x64 = 512 float4, 128 thr
            int slot = tid + i * 128;
            int r = slot >> 4, c4 = (slot & 15) * 4;
            float4 v = *(const float4*)&x[(size_t)(s0 + r) * DMODEL + k0 + c4];
            *(float4*)&xs[r][c4] = v;
        }
#pragma unroll
        for (int i = 0; i < 8; ++i) {  // wg chunk: 64x64 = 1024 float4
            int slot = tid + i * 128;
            int r = slot >> 4, c4 = (slot & 15) * 4;
            float4 v = *(const float4*)&wg[(size_t)r * DMODEL + k0 + c4];
            *(float4*)&wsh[r][c4] = v;
        }
        __syncthreads();
#pragma unroll
        for (int k4 = 0; k4 < 64; k4 += 4) {
            float4 xv[4], wv[4];
#pragma unroll
            for (int t = 0; t < 4; ++t) xv[t] = *(float4*)&xs[ty * 4 + t][k4];
#pragma unroll
            for (int j = 0; j < 4; ++j) wv[j] = *(float4*)&wsh[g + 16 * j][k4];
#pragma unroll
            for (int t = 0; t < 4; ++t)
#pragma unroll
                for (int j = 0; j < 4; ++j) {
                    // k-ascending chain per output: bit-identical across rounds
                    acc[t][j] += xv[t].x * wv[j].x; acc[t][j] += xv[t].y * wv[j].y;
                    acc[t][j] += xv[t].z * wv[j].z; acc[t][j] += xv[t].w * wv[j].w;
                }
        }
        __syncthreads();
    }

    // ---- in-block softmax: park logits tile in xs (all xs reads are done) ----
#pragma unroll
    for (int t = 0; t < 4; ++t)
#pragma unroll
        for (int j = 0; j < 4; ++j)
            xs[ty * 4 + t][g + 16 * j] = acc[t][j];
    __syncthreads();

    const int lane = tid & 63;        // lane == expert
    const int w = tid >> 6;           // wave handles tokens w*16 .. w*16+15
    float me_acc = 0.f;
#pragma unroll
    for (int it = 0; it < 16; ++it) {
        const int trow = w * 16 + it;
        float v = xs[trow][lane];
        float m = v;
#pragma unroll
        for (int off = 32; off; off >>= 1) m = fmaxf(m, __shfl_xor(m, off));
        float ev = expf(v - m);
        float sum = ev;
#pragma unroll
        for (int off = 32; off; off >>= 1) sum += __shfl_xor(sum, off);
        float gate = ev / sum;
        me_acc += gate;

        float bv = gate; int bi = lane;
#pragma unroll
        for (int off = 32; off; off >>= 1) {
            float ov = __shfl_xor(bv, off);
            int   oi = __shfl_xor(bi, off);
            if (ov > bv || (ov == bv && oi < bi)) { bv = ov; bi = oi; }
        }
        if (lane == 0) {
            const int s = s0 + trow;
            tok_expert[s] = bi;
            tok_gate[s]   = bv;
            tok_noise[s]  = jax_uniform_noise((unsigned)(s * NEXP + bi));
        }
    }
    mep[w][lane] = me_acc;
    __syncthreads();
    if (tid < 64)
        me_part[(size_t)blockIdx.x * 64 + tid] = mep[0][tid] + mep[1][tid];
}

// ---- Kernel 2: blocks 0..63 per-expert top-capacity select + scatter;
// ---- block 64: self-sufficient finalize (own LDS histogram + me_part reduce).
#define MAXN 2048
__global__ __launch_bounds__(256) void select_finalize(const int* __restrict__ tok_expert,
                                                       const float* __restrict__ tok_gate,
                                                       const float* __restrict__ tok_noise,
                                                       const float* __restrict__ me_part,
                                                       float* __restrict__ d_out) {
    if (blockIdx.x == NEXP) {
        __shared__ int hist[NEXP];
        if (threadIdx.x < NEXP) hist[threadIdx.x] = 0;
        __syncthreads();
        for (int s = threadIdx.x; s < S_TOK; s += 256)
            atomicAdd(&hist[tok_expert[s]], 1);
        __syncthreads();
        if (threadIdx.x < 64) {
            const int e = threadIdx.x;
            float me = 0.f;
            for (int b = 0; b < 256; ++b) me += me_part[(size_t)b * 64 + e];
            me /= (float)S_TOK;
            int c = hist[e];
            float ce = (float)c / (float)S_TOK;
            float p = me * ce;
#pragma unroll
            for (int off = 32; off; off >>= 1) p += __shfl_xor(p, off);
            if (e == 0) d_out[0] = p * (float)NEXP;
            d_out[1 + 2 * COMBINE_ELEMS + e] = (float)c;
        }
        return;
    }

    const int e = blockIdx.x;
    __shared__ int   toks[MAXN];
    __shared__ float noi[MAXN];
    __shared__ int   rnk[MAXN];
    __shared__ int   n_sh;
    if (threadIdx.x == 0) n_sh = 0;
    __syncthreads();

    for (int s = threadIdx.x; s < S_TOK; s += 256) {
        if (tok_expert[s] == e) {
            int i = atomicAdd(&n_sh, 1);
            if (i < MAXN) { toks[i] = s; noi[i] = tok_noise[s]; }
        }
    }
    __syncthreads();
    int n = n_sh; if (n > MAXN) n = MAXN;

    // rank by noise desc, ties -> lower token index (lax.top_k stability)
    for (int i = threadIdx.x; i < n; i += 256) {
        float vi = noi[i]; int si = toks[i];
        int r = 0;
        for (int j = 0; j < n; ++j) {
            float vj = noi[j];
            r += (vj > vi) || (vj == vi && toks[j] < si);
        }
        rnk[i] = r;
    }
    __syncthreads();

    for (int i = threadIdx.x; i < n; i += 256) {
        if (rnk[i] < CAP) {
            int si = toks[i];
            int loc = 0;  // cumsum slot among kept tokens, by token index
            for (int j = 0; j < n; ++j)
                loc += (rnk[j] < CAP) && (toks[j] < si);
            size_t base = 1ULL + (((size_t)si * NEXP + e) * CAP + (size_t)loc);
            d_out[base] = tok_gate[si];              // combine_weights
            d_out[base + COMBINE_ELEMS] = 1.0f;      // dispatch_mask
        }
    }
}

extern "C" void kernel_launch(void* const* d_in, const int* in_sizes, int n_in,
                              void* d_out, int out_size, void* d_ws, size_t ws_size,
                              hipStream_t stream) {
    const float* x  = (const float*)d_in[0];
    const float* wg = (const float*)d_in[1];
    float* out = (float*)d_out;
    float* ws  = (float*)d_ws;

    // ws layout (float offsets); all regions fully written each launch, no memsets.
    int*   tok_expert = (int*)ws;           // 8192
    float* tok_gate   = ws + 8192;          // 8192
    float* tok_noise  = ws + 16384;         // 8192
    float* me_part    = ws + 24576;         // 256*64

    gemm_softmax_zero<<<GEMM_BLOCKS + ZERO_BLOCKS, 128, 0, stream>>>(
        x, wg, tok_expert, tok_gate, tok_noise, me_part, out);
    select_finalize<<<NEXP + 1, 256, 0, stream>>>(tok_expert, tok_gate, tok_noise,
                                                  me_part, out);
}